// Round 8
// baseline (7135.676 us; speedup 1.0000x reference)
//
#include <hip/hip_runtime.h>
#include <math.h>

#define NT     365
#define NGRID  3000
#define NX     20
#define H      256
#define CPB    30
#define NPAIR  100
#define NBLK   (2*NPAIR)       // 200 blocks: pair p = b>>1, half = b&1
#define THREADS 512            // 8 waves
#define MT     2               // m-tiles (32 rows, 30 used)

// workspace layout (see kernel_launch)
#define WPK_US   (2*8*16*4*64*8)   // 524,288 us: [half][g_loc][kap][q][lane][e]
#define WPKIN_US (16*2*64*8)       // 16,384 us
#define HX_US    (NBLK*2*CPB*128)  // 1,536,000 us: per-block dbuf h-halves
#define YB_F     (NBLK*2*32)       // y partials
#define HX_ZERO_U32 (HX_US/2)      // 768,000

typedef short v8s __attribute__((ext_vector_type(8)));
typedef float v4f __attribute__((ext_vector_type(4)));
#define MFMA_BF16 __builtin_amdgcn_mfma_f32_16x16x32_bf16

__device__ __forceinline__ unsigned short f2bf(float f) {
    unsigned int u = __float_as_uint(f);
    u += 0x7fffu + ((u >> 16) & 1u);          // RTNE
    return (unsigned short)(u >> 16);
}
__device__ __forceinline__ float bf2f(unsigned short h) {
    return __uint_as_float(((unsigned int)h) << 16);
}
__device__ __forceinline__ float sigm(float x)  { return 1.0f / (1.0f + __expf(-x)); }
__device__ __forceinline__ float tanh_f(float x){ return 2.0f * sigm(2.0f * x) - 1.0f; }

// ---------------- weight pre-pack ----------------
__global__ void prep_kernel(const float* __restrict__ w_in,
                            const float* __restrict__ w_ih,
                            const float* __restrict__ w_hh,
                            const float* __restrict__ b_ih,
                            const float* __restrict__ b_hh,
                            unsigned short* __restrict__ wpk,
                            unsigned short* __restrict__ wpkin,
                            float* __restrict__ bsum) {
    int idx = blockIdx.x * 256 + threadIdx.x;
    if (idx < WPK_US) {
        int e    = idx & 7;
        int lane = (idx >> 3) & 63;
        int q    = (idx >> 9) & 3;
        int kap  = (idx >> 11) & 15;
        int g    = (idx >> 15) & 7;
        int half = (idx >> 18) & 1;
        int k = kap * 32 + ((lane >> 4) << 3) + e;
        int j = q * 256 + half * 128 + g * 16 + (lane & 15);
        float wv = (k < 256) ? w_ih[j * 256 + k] : w_hh[j * 256 + (k - 256)];
        wpk[idx] = f2bf(wv);             // hi only
    }
    if (idx < WPKIN_US) {
        int e    = idx & 7;
        int lane = (idx >> 3) & 63;
        int d    = (idx >> 9) & 1;
        int tau  = idx >> 10;            // 0..15
        int k = ((lane >> 4) << 3) + e;
        int n = tau * 16 + (lane & 15);
        float wv = (k < NX + 1) ? w_in[n * (NX + 1) + k] : 0.0f;
        unsigned short hi = f2bf(wv);
        wpkin[idx] = d ? f2bf(wv - bf2f(hi)) : hi;
    }
    if (idx < 4 * H) bsum[idx] = b_ih[idx] + b_hh[idx];
}

// zero comm buffers (d_ws is re-poisoned 0xAA before every timed launch)
__global__ void init_kernel(unsigned int* __restrict__ hx_u32,
                            float* __restrict__ ybuf,
                            unsigned int* __restrict__ flags) {
    int idx = blockIdx.x * 256 + threadIdx.x;
    for (int i = idx; i < HX_ZERO_U32; i += gridDim.x * 256) hx_u32[i] = 0u;
    if (idx < YB_F) ybuf[idx] = 0.0f;
    if (idx < NBLK) flags[idx] = 0u;
}

// ---------------- main persistent LSTM (paired j-split) ----------------
// 200 blocks, 1 block/CU (LDS pad) -> all co-resident, pair spins are safe.
// waves_per_eu(2,2): 256-VGPR budget, B-prefetch dbuf cannot spill.
__global__ __attribute__((amdgpu_flat_work_group_size(THREADS, THREADS),
                          amdgpu_waves_per_eu(2, 2)))
void lstm_main(const float* __restrict__ x,
               const float* __restrict__ y,
               const float* __restrict__ b_in,
               const float* __restrict__ w_out,
               const float* __restrict__ b_out,
               const unsigned short* __restrict__ wpk,
               const unsigned short* __restrict__ wpkin,
               const float* __restrict__ bsum,
               unsigned short* __restrict__ hx,
               float* __restrict__ ybuf,
               unsigned int* __restrict__ flags,
               float* __restrict__ out) {
    __shared__ __align__(16) unsigned short Agh[MT][16][512];  // 32 KB
    __shared__ __align__(16) unsigned short Agl[MT][16][512];  // 32 KB
    __shared__ __align__(16) unsigned short Xh[MT][512];
    __shared__ __align__(16) unsigned short Xl[MT][512];
    __shared__ float y_part[8][32];
    __shared__ float y_own_s[32];
    __shared__ float lds_pad[2816];    // total ~82 KB -> 1 block/CU

    const int tid  = threadIdx.x;
    const int w    = tid >> 6;          // wave 0..7
    const int lane = tid & 63;
    const int col  = lane & 15;
    const int quad = lane >> 4;
    const int b    = blockIdx.x;
    const int p    = b >> 1;
    const int half = b & 1;
    const int pb   = b ^ 1;             // partner block
    const int g0   = p * CPB;

    // per-wave constants (own gate columns: jh = half*128 + w*16 + col)
    const int   jho    = w * 16 + col;            // 0..127 within half
    const int   jh_own = half * 128 + jho;
    const float b_i  = bsum[jh_own];
    const float b_f  = bsum[256 + jh_own];
    const float b_g  = bsum[512 + jh_own];
    const float b_o  = bsum[768 + jh_own];
    const float wo   = w_out[jh_own];
    const float bout = b_out[0];
    const int   kq_h = 8 + 4 * half + (w >> 1);   // own h plane
    const int   qp_h = (2 * w + (col >> 3)) & 3;
    const int   e_h  = col & 7;
    // X phase: wave w handles tiles tau = 2w, 2w+1 (both write plane kq=w)
    const float bi_x0 = b_in[2 * w * 16 + col];
    const float bi_x1 = b_in[(2 * w + 1) * 16 + col];
    const int   qp_x0 = (4 * w + (col >> 3)) & 3;
    const int   qp_x1 = (4 * w + 2 + (col >> 3)) & 3;

    const unsigned short* bbase = wpk + ((size_t)(half * 8 + w) * 16) * 4 * 512 + lane * 8;

    if (bout == -1234567.25f) {     // keep lds_pad alive (never true)
        lds_pad[tid] = (float)tid; lds_pad[tid + 512] = 1.f;
        lds_pad[tid + 1024] = 2.f; lds_pad[tid + 1536] = 3.f; lds_pad[tid + 2048] = 4.f;
    }

    // zero-init LDS
    {
        unsigned int* q_;
        q_ = (unsigned int*)&Agh[0][0][0];
        for (int i = tid; i < MT * 16 * 256; i += THREADS) q_[i] = 0u;
        q_ = (unsigned int*)&Agl[0][0][0];
        for (int i = tid; i < MT * 16 * 256; i += THREADS) q_[i] = 0u;
        q_ = (unsigned int*)&Xh[0][0];
        for (int i = tid; i < MT * 256; i += THREADS) q_[i] = 0u;
        q_ = (unsigned int*)&Xl[0][0];
        for (int i = tid; i < MT * 256; i += THREADS) q_[i] = 0u;
        if (tid < 32) y_own_s[tid] = 0.0f;
    }
    float c_st[MT][4];
    #pragma unroll
    for (int m = 0; m < MT; ++m)
        #pragma unroll
        for (int r = 0; r < 4; ++r) c_st[m][r] = 0.0f;
    __syncthreads();

    for (int t = 0; t < NT; ++t) {
        // ---- W: wait for partner h(t-1)
        if (tid == 0) {
            while (__hip_atomic_load(&flags[pb], __ATOMIC_ACQUIRE,
                                     __HIP_MEMORY_SCOPE_AGENT) < (unsigned)t) { }
        }
        __syncthreads();

        // ---- P1a: copy partner h(t-1) into its A planes (hi only; lo stays 0)
        {
            const unsigned short* hx_p =
                hx + ((size_t)pb * 2 + ((t + 1) & 1)) * (CPB * 128);
            int phalf = half ^ 1;
            for (int i = tid; i < CPB * 128; i += THREADS) {
                unsigned short v = hx_p[i];
                int cell = i >> 7, jo = i & 127;
                int jp = phalf * 128 + jo;
                int mt = cell >> 4, cellm = cell & 15;
                int kq = 8 + (jp >> 5);
                int pos = ((((jp >> 3) & 3) * 16 + cellm) << 3) + (jp & 7);
                Agh[mt][kq][pos] = v;
            }
        }
        // ---- P1b: finalize y(t-1): out + feedback (skip at t=0; y0 = 0)
        if (tid < CPB) {
            if (t > 0) {
                float yv = bout + y_own_s[tid] +
                           ybuf[((size_t)pb * 2 + ((t + 1) & 1)) * 32 + tid];
                if (half == 0) out[(size_t)(t - 1) * NGRID + g0 + tid] = yv;
                int mt = tid >> 4, m = tid & 15;
                int pos = (2 * 16 + m) * 8 + 4;           // k = 20
                unsigned short hi = f2bf(yv);
                Xh[mt][pos] = hi;
                Xl[mt][pos] = f2bf(yv - bf2f(hi));
            }
        }
        // ---- P1c: stage x(t); obs overwrite of yt
        {
            const float* xr = x + ((size_t)t * NGRID + g0) * NX;
            for (int i = tid; i < CPB * NX; i += THREADS) {
                float v  = xr[i];
                int cell = i / NX;
                int k    = i - cell * NX;
                int mt   = cell >> 4, m = cell & 15;
                int pos  = (((k >> 3) << 4) + m) * 8 + (k & 7);
                unsigned short hi = f2bf(v);
                Xh[mt][pos] = hi;
                Xl[mt][pos] = f2bf(v - bf2f(hi));
            }
            if (tid < CPB) {
                float yo = y[(size_t)t * NGRID + g0 + tid];
                if (!__builtin_isnan(yo)) {
                    int mt = tid >> 4, m = tid & 15;
                    int pos = (2 * 16 + m) * 8 + 4;
                    unsigned short hi = f2bf(yo);
                    Xh[mt][pos] = hi;
                    Xl[mt][pos] = f2bf(yo - bf2f(hi));
                }
            }
        }
        __syncthreads();

        // ---- X: x0 = relu(xcat @ w_in^T + b_in), full 256 cols (both halves)
        {
            #pragma unroll
            for (int i = 0; i < 4; ++i) {
                int tau = 2 * w + (i >> 1);
                int mt  = i & 1;
                v8s xah = *(const v8s*)&Xh[mt][lane * 8];
                v8s xal = *(const v8s*)&Xl[mt][lane * 8];
                v8s bh  = *(const v8s*)(wpkin + (tau * 2 + 0) * 512 + lane * 8);
                v8s bl  = *(const v8s*)(wpkin + (tau * 2 + 1) * 512 + lane * 8);
                v4f acc = {0.0f, 0.0f, 0.0f, 0.0f};
                acc = MFMA_BF16(xah, bh, acc, 0, 0, 0);
                acc = MFMA_BF16(xah, bl, acc, 0, 0, 0);
                acc = MFMA_BF16(xal, bh, acc, 0, 0, 0);
                float bi = (i < 2) ? bi_x0 : bi_x1;
                int qp   = (i < 2) ? qp_x0 : qp_x1;
                #pragma unroll
                for (int r = 0; r < 4; ++r) {
                    int cellm = quad * 4 + r;
                    int cell  = mt * 16 + cellm;
                    if (cell < CPB) {
                        float v = fmaxf(acc[r] + bi, 0.0f);
                        unsigned short hi = f2bf(v);
                        int pos = (qp * 16 + cellm) * 8 + (col & 7);
                        Agh[mt][w][pos] = hi;
                        Agl[mt][w][pos] = f2bf(v - bf2f(hi));
                    }
                }
            }
        }
        __syncthreads();

        // ---- G: gates GEMM, own 16 cols per q (2-term AhBh + AlBh, B dbuf)
        v4f acc[MT][4];
        #pragma unroll
        for (int mt = 0; mt < MT; ++mt)
            #pragma unroll
            for (int q = 0; q < 4; ++q) acc[mt][q] = (v4f){0, 0, 0, 0};

        {
            v8s Bn[4];
            #pragma unroll
            for (int c = 0; c < 4; ++c)
                Bn[c] = *(const v8s*)(bbase + c * 512);
            #pragma unroll 2
            for (int kap = 0; kap < 16; ++kap) {
                v8s Bc[4];
                #pragma unroll
                for (int c = 0; c < 4; ++c) Bc[c] = Bn[c];
                if (kap < 15) {
                    const unsigned short* bp = bbase + (size_t)(kap + 1) * 2048;
                    #pragma unroll
                    for (int c = 0; c < 4; ++c)
                        Bn[c] = *(const v8s*)(bp + c * 512);
                }
                v8s Ah[MT], Al[MT];
                #pragma unroll
                for (int mt = 0; mt < MT; ++mt) {
                    Ah[mt] = *(const v8s*)&Agh[mt][kap][lane * 8];
                    Al[mt] = *(const v8s*)&Agl[mt][kap][lane * 8];
                }
                #pragma unroll
                for (int q = 0; q < 4; ++q) {
                    #pragma unroll
                    for (int mt = 0; mt < MT; ++mt) {
                        acc[mt][q] = MFMA_BF16(Ah[mt], Bc[q], acc[mt][q], 0, 0, 0);
                        acc[mt][q] = MFMA_BF16(Al[mt], Bc[q], acc[mt][q], 0, 0, 0);
                    }
                }
            }
        }
        __syncthreads();   // all A reads done -> safe to overwrite own h slots

        // ---- E: pointwise LSTM, own h -> LDS + global exchange, y partial
        {
            unsigned short* hx_o =
                hx + ((size_t)b * 2 + (t & 1)) * (CPB * 128);
            float yp[MT][4];
            #pragma unroll
            for (int mt = 0; mt < MT; ++mt) {
                #pragma unroll
                for (int r = 0; r < 4; ++r) {
                    int cellm = quad * 4 + r;
                    int cell  = mt * 16 + cellm;
                    float iv = acc[mt][0][r] + b_i;
                    float fv = acc[mt][1][r] + b_f;
                    float gv = acc[mt][2][r] + b_g;
                    float ov = acc[mt][3][r] + b_o;
                    float c  = fmaf(sigm(fv), c_st[mt][r], sigm(iv) * tanh_f(gv));
                    c_st[mt][r] = c;
                    float h  = sigm(ov) * tanh_f(c);
                    yp[mt][r] = 0.0f;
                    if (cell < CPB) {
                        unsigned short hi = f2bf(h);
                        int pos = (qp_h * 16 + cellm) * 8 + e_h;
                        Agh[mt][kq_h][pos] = hi;
                        Agl[mt][kq_h][pos] = f2bf(h - bf2f(hi));
                        hx_o[cell * 128 + jho] = hi;
                        yp[mt][r] = h * wo;
                    }
                }
            }
            #pragma unroll
            for (int mt = 0; mt < MT; ++mt)
                #pragma unroll
                for (int r = 0; r < 4; ++r) {
                    float psum = yp[mt][r];
                    psum += __shfl_xor(psum, 1);
                    psum += __shfl_xor(psum, 2);
                    psum += __shfl_xor(psum, 4);
                    psum += __shfl_xor(psum, 8);
                    if (col == 0)
                        y_part[w][mt * 16 + quad * 4 + r] = psum;
                }
        }
        __syncthreads();

        // ---- S: y own-half sum, publish, signal
        if (tid < CPB) {
            float s = 0.0f;
            #pragma unroll
            for (int w2 = 0; w2 < 8; ++w2) s += y_part[w2][tid];
            y_own_s[tid] = s;
            ybuf[((size_t)b * 2 + (t & 1)) * 32 + tid] = s;
        }
        __syncthreads();
        if (tid == 0) {
            __threadfence();
            __hip_atomic_store(&flags[b], (unsigned)(t + 1), __ATOMIC_RELEASE,
                               __HIP_MEMORY_SCOPE_AGENT);
        }
    }

    // ---- final output row (t = NT-1)
    if (tid == 0) {
        while (__hip_atomic_load(&flags[pb], __ATOMIC_ACQUIRE,
                                 __HIP_MEMORY_SCOPE_AGENT) < (unsigned)NT) { }
    }
    __syncthreads();
    if (half == 0 && tid < CPB) {
        float yv = bout + y_own_s[tid] +
                   ybuf[((size_t)pb * 2 + ((NT - 1) & 1)) * 32 + tid];
        out[(size_t)(NT - 1) * NGRID + g0 + tid] = yv;
    }

    if (bout == -1234567.25f)
        out[tid & 3] += lds_pad[tid] + lds_pad[tid + 1024] + lds_pad[tid + 2048];
}

extern "C" void kernel_launch(void* const* d_in, const int* in_sizes, int n_in,
                              void* d_out, int out_size, void* d_ws, size_t ws_size,
                              hipStream_t stream) {
    const float* x     = (const float*)d_in[0];
    const float* y     = (const float*)d_in[1];
    const float* w_in  = (const float*)d_in[2];
    const float* b_in  = (const float*)d_in[3];
    const float* w_ih  = (const float*)d_in[4];
    const float* b_ih  = (const float*)d_in[5];
    const float* w_hh  = (const float*)d_in[6];
    const float* b_hh  = (const float*)d_in[7];
    const float* w_out = (const float*)d_in[8];
    const float* b_out = (const float*)d_in[9];

    unsigned short* wpk   = (unsigned short*)d_ws;
    unsigned short* wpkin = wpk + WPK_US;
    float*          bsum  = (float*)(wpkin + WPKIN_US);
    unsigned short* hx    = (unsigned short*)(bsum + 1024);
    float*          ybuf  = (float*)(hx + HX_US);
    unsigned int*   flags = (unsigned int*)(ybuf + YB_F);
    float*          out   = (float*)d_out;

    prep_kernel<<<(WPK_US + 255) / 256, 256, 0, stream>>>(
        w_in, w_ih, w_hh, b_ih, b_hh, wpk, wpkin, bsum);
    init_kernel<<<3000, 256, 0, stream>>>((unsigned int*)hx, ybuf, flags);
    lstm_main<<<NBLK, THREADS, 0, stream>>>(
        x, y, b_in, w_out, b_out, wpk, wpkin, bsum, hx, ybuf, flags, out);
}

// Round 9
// 4424.863 us; speedup vs baseline: 1.6126x; 1.6126x over previous
//
#include <hip/hip_runtime.h>
#include <math.h>

#define NT     365
#define NGRID  3000
#define NX     20
#define H      256
#define CPB    15
#define NBLK   (NGRID/CPB)     // 200 blocks, 1 per CU
#define THREADS 1024           // 16 waves, 4 per SIMD

// packed weight sizes (ushorts)
// wpk HI-ONLY: [g 16][kap 16][q 4][lane 64][e 8]
#define WPK_US   (16*16*4*64*8)   // 524,288
#define WPKIN_US (16*2*64*8)      // 16,384

typedef short v8s __attribute__((ext_vector_type(8)));
typedef float v4f __attribute__((ext_vector_type(4)));
#define MFMA_BF16 __builtin_amdgcn_mfma_f32_16x16x32_bf16

__device__ __forceinline__ unsigned short f2bf(float f) {
    unsigned int u = __float_as_uint(f);
    u += 0x7fffu + ((u >> 16) & 1u);          // RTNE
    return (unsigned short)(u >> 16);
}
__device__ __forceinline__ float bf2f(unsigned short h) {
    return __uint_as_float(((unsigned int)h) << 16);
}
__device__ __forceinline__ float sigm(float x)  { return 1.0f / (1.0f + __expf(-x)); }
__device__ __forceinline__ float tanh_f(float x){ return 2.0f * sigm(2.0f * x) - 1.0f; }

// ---------------- weight pre-pack (same as R7) ----------------
__global__ void prep_kernel(const float* __restrict__ w_in,
                            const float* __restrict__ w_ih,
                            const float* __restrict__ w_hh,
                            const float* __restrict__ b_ih,
                            const float* __restrict__ b_hh,
                            unsigned short* __restrict__ wpk,
                            unsigned short* __restrict__ wpkin,
                            float* __restrict__ bsum) {
    int idx = blockIdx.x * 256 + threadIdx.x;
    if (idx < WPK_US) {
        int e    = idx & 7;
        int lane = (idx >> 3) & 63;
        int q    = (idx >> 9) & 3;
        int gk   = idx >> 11;            // 0..255
        int kap  = gk & 15, g = gk >> 4;
        int k = kap * 32 + ((lane >> 4) << 3) + e;
        int j = q * 256 + g * 16 + (lane & 15);
        float wv = (k < 256) ? w_ih[j * 256 + k] : w_hh[j * 256 + (k - 256)];
        wpk[idx] = f2bf(wv);             // hi only
    }
    if (idx < WPKIN_US) {
        int e    = idx & 7;
        int lane = (idx >> 3) & 63;
        int d    = (idx >> 9) & 1;
        int tau  = idx >> 10;            // 0..15
        int k = ((lane >> 4) << 3) + e;
        int n = tau * 16 + (lane & 15);
        float wv = (k < NX + 1) ? w_in[n * (NX + 1) + k] : 0.0f;
        unsigned short hi = f2bf(wv);
        wpkin[idx] = d ? f2bf(wv - bf2f(hi)) : hi;
    }
    if (idx < 4 * H) bsum[idx] = b_ih[idx] + b_hh[idx];
}

// ---------------- main persistent LSTM ----------------
// R8 lesson: cross-block h-exchange pays HBM-latency fences (agent-scope
// release forces per-XCD L2 writeback) -> reverted to self-contained blocks.
// This round: CPB 30->15, 200 blocks. Per-CU weight stream (the 6.8 us/step
// floor) is CPB-invariant; the VALU phases (X/E/P1) halve, and 200 CUs work.
// MT=1 (16-row tile, 15 used). LDS pad >80 KB -> 1 block/CU.
__global__ __attribute__((amdgpu_flat_work_group_size(THREADS, THREADS),
                          amdgpu_waves_per_eu(4, 4)))
void lstm_main(const float* __restrict__ x,
               const float* __restrict__ y,
               const float* __restrict__ b_in,
               const float* __restrict__ w_out,
               const float* __restrict__ b_out,
               const unsigned short* __restrict__ wpk,
               const unsigned short* __restrict__ wpkin,
               const float* __restrict__ bsum,
               float* __restrict__ out) {
    // fragment-major activation buffers: [kap][lane*8+e], lane = qp*16 + m
    __shared__ __align__(16) unsigned short Agh[16][512];   // 16 KB
    __shared__ __align__(16) unsigned short Agl[16][512];   // 16 KB
    __shared__ __align__(16) unsigned short Xh[512];        // 1 KB
    __shared__ __align__(16) unsigned short Xl[512];        // 1 KB
    __shared__ float y_part[16][16];
    __shared__ float lds_pad[12288];    // total ~84 KB -> 1 block/CU

    const int tid  = threadIdx.x;
    const int w    = tid >> 6;          // wave 0..15; owns output group g = w
    const int lane = tid & 63;
    const int col  = lane & 15;
    const int quad = lane >> 4;
    const int g0   = blockIdx.x * CPB;

    // per-wave constants: lane owns hidden index jh = w*16 + col
    const int   jh   = w * 16 + col;
    const float b_i  = bsum[jh];
    const float b_f  = bsum[256 + jh];
    const float b_g  = bsum[512 + jh];
    const float b_o  = bsum[768 + jh];
    const float wo   = w_out[jh];
    const float bi_x = b_in[jh];
    const float bout = b_out[0];
    const int   kq_x = jh >> 5;                   // = w>>1, x0 write plane
    const int   kq_h = 8 + (jh >> 5);             // h write plane
    const int   qp_w = (jh >> 3) & 3;
    const int   e_w  = jh & 7;
    const unsigned short* bbase = wpk + (size_t)(w * 16) * 4 * 512 + lane * 8;
    const unsigned short* bx_hi = wpkin + (w * 2 + 0) * 512 + lane * 8;
    const unsigned short* bx_lo = wpkin + (w * 2 + 1) * 512 + lane * 8;

    if (bout == -1234567.25f) {     // keep lds_pad alive (never true)
        lds_pad[tid] = (float)tid;
        lds_pad[tid + 4096] = 1.f;
        lds_pad[tid + 8192] = 2.f;
    }

    // zero-init LDS (h planes must be 0 at t=0; pad cols stay 0 forever)
    {
        unsigned int* p;
        p = (unsigned int*)&Agh[0][0];
        for (int i = tid; i < 16 * 256; i += THREADS) p[i] = 0u;
        p = (unsigned int*)&Agl[0][0];
        for (int i = tid; i < 16 * 256; i += THREADS) p[i] = 0u;
        if (tid < 256) ((unsigned int*)&Xh[0])[tid] = 0u;
        if (tid < 256) ((unsigned int*)&Xl[0])[tid] = 0u;
    }
    float c_st[4];
    #pragma unroll
    for (int r = 0; r < 4; ++r) c_st[r] = 0.0f;
    __syncthreads();

    for (int t = 0; t < NT; ++t) {
        // ---- P1: stage x[t] (bf16 hi/lo, frag-major) + observed y fill
        {
            const float* xr = x + ((size_t)t * NGRID + g0) * NX;
            if (tid < CPB * NX) {
                float v  = xr[tid];
                int cell = tid / NX;
                int k    = tid - cell * NX;
                int pos  = (((k >> 3) << 4) + cell) * 8 + (k & 7);
                unsigned short hi = f2bf(v);
                Xh[pos] = hi;
                Xl[pos] = f2bf(v - bf2f(hi));
            }
            if (tid < CPB) {
                float yo = y[(size_t)t * NGRID + g0 + tid];
                if (!__builtin_isnan(yo)) {
                    int pos = (2 * 16 + tid) * 8 + 4;     // k = 20
                    unsigned short hi = f2bf(yo);
                    Xh[pos] = hi;
                    Xl[pos] = f2bf(yo - bf2f(hi));
                }
            }
        }
        __syncthreads();

        // ---- X: x0 = relu(xcat @ w_in^T + b_in) via MFMA (wave w -> tau = w)
        {
            v8s bh  = *(const v8s*)bx_hi;
            v8s bl  = *(const v8s*)bx_lo;
            v8s xah = *(const v8s*)&Xh[lane * 8];
            v8s xal = *(const v8s*)&Xl[lane * 8];
            v4f acc = {0.0f, 0.0f, 0.0f, 0.0f};
            acc = MFMA_BF16(xah, bh, acc, 0, 0, 0);
            acc = MFMA_BF16(xah, bl, acc, 0, 0, 0);
            acc = MFMA_BF16(xal, bh, acc, 0, 0, 0);
            #pragma unroll
            for (int r = 0; r < 4; ++r) {
                int cell = quad * 4 + r;
                if (cell < CPB) {
                    float v = fmaxf(acc[r] + bi_x, 0.0f);
                    unsigned short hi = f2bf(v);
                    int pos = (qp_w * 16 + cell) * 8 + e_w;
                    Agh[kq_x][pos] = hi;
                    Agl[kq_x][pos] = f2bf(v - bf2f(hi));
                }
            }
        }
        __syncthreads();

        // ---- G: gates GEMM (2-term AhBh + AlBh, weights hi-only)
        v4f acc[4];
        #pragma unroll
        for (int q = 0; q < 4; ++q) acc[q] = (v4f){0, 0, 0, 0};

        #pragma unroll 1
        for (int kap = 0; kap < 16; ++kap) {
            const unsigned short* bp = bbase + (size_t)kap * 4 * 512;
            v8s B[4];
            #pragma unroll
            for (int c = 0; c < 4; ++c)
                B[c] = *(const v8s*)(bp + c * 512);
            v8s Ah = *(const v8s*)&Agh[kap][lane * 8];
            v8s Al = *(const v8s*)&Agl[kap][lane * 8];
            #pragma unroll
            for (int q = 0; q < 4; ++q) {
                acc[q] = MFMA_BF16(Ah, B[q], acc[q], 0, 0, 0);
                acc[q] = MFMA_BF16(Al, B[q], acc[q], 0, 0, 0);
            }
        }
        __syncthreads();   // all A reads done -> safe to overwrite h planes

        // ---- E: pointwise LSTM + h writeback + y partial
        {
            float yp[4];
            #pragma unroll
            for (int r = 0; r < 4; ++r) {
                int cell = quad * 4 + r;
                float iv = acc[0][r] + b_i;
                float fv = acc[1][r] + b_f;
                float gv = acc[2][r] + b_g;
                float ov = acc[3][r] + b_o;
                float c  = fmaf(sigm(fv), c_st[r], sigm(iv) * tanh_f(gv));
                c_st[r]  = c;
                float h  = sigm(ov) * tanh_f(c);
                yp[r] = 0.0f;
                if (cell < CPB) {
                    unsigned short hi = f2bf(h);
                    int pos = (qp_w * 16 + cell) * 8 + e_w;
                    Agh[kq_h][pos] = hi;
                    Agl[kq_h][pos] = f2bf(h - bf2f(hi));
                    yp[r] = h * wo;
                }
            }
            #pragma unroll
            for (int r = 0; r < 4; ++r) {
                float p = yp[r];
                p += __shfl_xor(p, 1);
                p += __shfl_xor(p, 2);
                p += __shfl_xor(p, 4);
                p += __shfl_xor(p, 8);
                if (col == 0)
                    y_part[w][quad * 4 + r] = p;
            }
        }
        __syncthreads();

        // ---- P5: finalize y, store, feed back into xcat k=20
        // (no loop-end barrier needed: next post-P1 barrier orders these
        //  writes vs the next X-phase reads; k=20 obs overwrite is same-thread)
        if (tid < CPB) {
            float yv = bout;
            #pragma unroll
            for (int w2 = 0; w2 < 16; ++w2) yv += y_part[w2][tid];
            out[(size_t)t * NGRID + g0 + tid] = yv;
            int pos = (2 * 16 + tid) * 8 + 4;             // k = 20
            unsigned short hi = f2bf(yv);
            Xh[pos] = hi;
            Xl[pos] = f2bf(yv - bf2f(hi));
        }
    }

    // keep-alive read for lds_pad (never executes)
    if (bout == -1234567.25f)
        out[tid & 3] += lds_pad[tid] + lds_pad[tid + 4096] + lds_pad[tid + 8192];
}

extern "C" void kernel_launch(void* const* d_in, const int* in_sizes, int n_in,
                              void* d_out, int out_size, void* d_ws, size_t ws_size,
                              hipStream_t stream) {
    const float* x     = (const float*)d_in[0];
    const float* y     = (const float*)d_in[1];
    const float* w_in  = (const float*)d_in[2];
    const float* b_in  = (const float*)d_in[3];
    const float* w_ih  = (const float*)d_in[4];
    const float* b_ih  = (const float*)d_in[5];
    const float* w_hh  = (const float*)d_in[6];
    const float* b_hh  = (const float*)d_in[7];
    const float* w_out = (const float*)d_in[8];
    const float* b_out = (const float*)d_in[9];

    unsigned short* wpk   = (unsigned short*)d_ws;
    unsigned short* wpkin = wpk + WPK_US;
    float*          bsum  = (float*)(wpkin + WPKIN_US);
    float*          out   = (float*)d_out;

    prep_kernel<<<(WPK_US + 255) / 256, 256, 0, stream>>>(
        w_in, w_ih, w_hh, b_ih, b_hh, wpk, wpkin, bsum);
    lstm_main<<<NBLK, THREADS, 0, stream>>>(
        x, y, b_in, w_out, b_out, wpk, wpkin, bsum, out);
}